// Round 6
// baseline (51.465 us; speedup 1.0000x reference)
//
#include <hip/hip_runtime.h>

// LSEP: loss = mean_i log1p( (sum_{n: partial=0} exp(q_n)) * (sum_{p: partial=1} exp(-q_p)) )
// q = T[i, bayes[i], :], T: [B,10,10] f32, bayes: [B] int32, partial: [B,10] int32.
//
// R6: single-kernel. R5's gather/LDS structure (BW-bound at ~90% of the
// 204-MB gather-granularity floor; occupancy proven non-binding), but the
// final reduce is one atomicAdd per block instead of a second dispatch.
// d_out zeroed via 4-B hipMemsetAsync (graph-capture safe).

#define NROWS   1000000
#define C       10
#define NCHUNKS 15625          // 64-row chunks
#define GRID    2048
#define WPB     4              // waves per block
#define NW      (GRID * WPB)   // 8192 waves
#define NIT     2              // ceil(NCHUNKS / NW)

__global__ __launch_bounds__(256, 8) void lsep_k1(const float* __restrict__ T,
                                                  const int* __restrict__ bayes,
                                                  const int* __restrict__ partial,
                                                  float* __restrict__ out) {
    __shared__ float qs[WPB][64][12];  // row stride 48 B: 16-B aligned reads
    __shared__ int   ps[WPB][640];     // [64][10] flat

    const int tid = threadIdx.x;
    const int l   = tid & 63;          // lane
    const int w   = tid >> 6;          // wave in block
    const int c2  = l & 7;             // float2 slot in row (active if < 5)
    const int g   = l >> 3;            // row subgroup 0..7

    float acc = 0.0f;

    for (int it = 0; it < NIT; ++it) {
        const int  ci    = blockIdx.x * WPB + w + it * NW;
        const bool valid = ci < NCHUNKS;
        const int  cbase = ci * 64;

        // ---- issue ALL VMEM first ----
        int bv = 0;
        if (valid) bv = bayes[cbase + l];              // coalesced, 64 rows

        int2 pv[5];
        if (valid) {
#pragma unroll
            for (int i = 0; i < 5; ++i)
                pv[i] = *reinterpret_cast<const int2*>(
                    partial + (size_t)cbase * C + 2 * (i * 64 + l));
        }

        float2 qv[8];
        if (valid && c2 < 5) {
#pragma unroll
            for (int k = 0; k < 8; ++k) {              // 8 gathers in flight
                const int row = cbase + k * 8 + g;
                const int b   = __shfl(bv, k * 8 + g, 64);
                qv[k] = *reinterpret_cast<const float2*>(
                    T + (size_t)row * (C * C) + b * C + 2 * c2);
            }
        }

        // ---- stage to this wave's LDS slice ----
        if (valid) {
#pragma unroll
            for (int i = 0; i < 5; ++i)
                *reinterpret_cast<int2*>(&ps[w][2 * (i * 64 + l)]) = pv[i];
            if (c2 < 5) {
#pragma unroll
                for (int k = 0; k < 8; ++k)
                    *reinterpret_cast<float2*>(&qs[w][k * 8 + g][2 * c2]) = qv[k];
            }
        }

        __syncthreads();

        // ---- per-lane row reduce: lane l owns row cbase + l ----
        if (valid) {
            float q[12];
            *reinterpret_cast<float4*>(&q[0]) = *reinterpret_cast<const float4*>(&qs[w][l][0]);
            *reinterpret_cast<float4*>(&q[4]) = *reinterpret_cast<const float4*>(&qs[w][l][4]);
            *reinterpret_cast<float2*>(&q[8]) = *reinterpret_cast<const float2*>(&qs[w][l][8]);

            int p[10];
#pragma unroll
            for (int i = 0; i < 5; ++i)
                *reinterpret_cast<int2*>(&p[2 * i]) =
                    *reinterpret_cast<const int2*>(&ps[w][10 * l + 2 * i]);

            float sn = 0.0f, sp = 0.0f;
#pragma unroll
            for (int e = 0; e < C; ++e) {
                const float ex = __expf(p[e] == 0 ? q[e] : -q[e]);
                sn += (p[e] == 0) ? ex : 0.0f;
                sp += (p[e] == 0) ? 0.0f : ex;
            }
            acc += log1pf(sn * sp);
        }

        __syncthreads();
    }

    // wave64 reduce, 4-wave LDS reduce, one atomic per block
#pragma unroll
    for (int m = 1; m < 64; m <<= 1) acc += __shfl_xor(acc, m, 64);

    __shared__ float wsum[WPB];
    if (l == 0) wsum[w] = acc;
    __syncthreads();
    if (tid == 0)
        atomicAdd(out, (wsum[0] + wsum[1] + wsum[2] + wsum[3]) * (1.0f / (float)NROWS));
}

extern "C" void kernel_launch(void* const* d_in, const int* in_sizes, int n_in,
                              void* d_out, int out_size, void* d_ws, size_t ws_size,
                              hipStream_t stream) {
    const float* T       = (const float*)d_in[0];
    const int*   bayes   = (const int*)d_in[1];
    const int*   partial = (const int*)d_in[2];
    float*       out     = (float*)d_out;

    hipMemsetAsync(d_out, 0, sizeof(float), stream);   // out is accumulated atomically
    lsep_k1<<<GRID, 256, 0, stream>>>(T, bayes, partial, out);
}

// Round 7
// 39.927 us; speedup vs baseline: 1.2890x; 1.2890x over previous
//
#include <hip/hip_runtime.h>

// LSEP: loss = mean_i log1p( (sum_{n: partial=0} exp(q_n)) * (sum_{p: partial=1} exp(-q_p)) )
// q = T[i, bayes[i], :], T: [B,10,10] f32, bayes: [B] int32, partial: [B,10] int32.
//
// R7: R4 structure (best, 40.6 us) + non-temporal loads on all global reads
// (each byte read exactly once; evict-first keeps L2 out of the way).
// Probes so far: occupancy 12->28 waves/CU null, all-VMEM-first null,
// atomic tail-merge negative. k1 sits at ~86% of the 204-MB scatter floor.

#define NROWS  1000000
#define C      10
#define NBLK   3125    // one-wave blocks
#define ITER   5       // 64-row chunks per block: 3125*5*64 = 1e6 exactly

typedef float f32x2 __attribute__((ext_vector_type(2)));
typedef int   i32x2 __attribute__((ext_vector_type(2)));

__global__ __launch_bounds__(64) void lsep_k1(const float* __restrict__ T,
                                              const int* __restrict__ bayes,
                                              const int* __restrict__ partial,
                                              float* __restrict__ bsum) {
    __shared__ float qs[64][12];   // gathered q rows, stride 48 B (16-B aligned rows)
    __shared__ int   ps[640];      // partial rows, flat [64][10]

    const int l  = threadIdx.x;
    const int c2 = l & 7;          // float2 slot within row (active if < 5)
    const int g  = l >> 3;         // row subgroup 0..7

    float acc = 0.0f;

    for (int t = 0; t < ITER; ++t) {
        const int rbase = (blockIdx.x * ITER + t) * 64;

        // ---- stage T gather: 8 instrs, 8 rows each, float2 per lane ----
#pragma unroll
        for (int k = 0; k < 8; ++k) {
            const int row = rbase + k * 8 + g;
            const int b   = __builtin_nontemporal_load(bayes + row);
            if (c2 < 5) {
                const f32x2 v = __builtin_nontemporal_load(
                    reinterpret_cast<const f32x2*>(T + (size_t)row * (C * C) + b * C + 2 * c2));
                *reinterpret_cast<f32x2*>(&qs[k * 8 + g][2 * c2]) = v;
            }
        }

        // ---- stage partial: fully coalesced, identity LDS layout ----
#pragma unroll
        for (int i = 0; i < 5; ++i) {
            const int m = i * 64 + l;                // int2 index 0..319
            const i32x2 v = __builtin_nontemporal_load(
                reinterpret_cast<const i32x2*>(partial + (size_t)rbase * C + 2 * m));
            *reinterpret_cast<i32x2*>(&ps[2 * m]) = v;
        }

        __syncthreads();

        // ---- per-lane row reduce (lane l owns row rbase + l) ----
        float q[12];
        *reinterpret_cast<float4*>(&q[0]) = *reinterpret_cast<const float4*>(&qs[l][0]);
        *reinterpret_cast<float4*>(&q[4]) = *reinterpret_cast<const float4*>(&qs[l][4]);
        *reinterpret_cast<float2*>(&q[8]) = *reinterpret_cast<const float2*>(&qs[l][8]);

        int p[10];
#pragma unroll
        for (int i = 0; i < 5; ++i)
            *reinterpret_cast<int2*>(&p[2 * i]) =
                *reinterpret_cast<const int2*>(&ps[10 * l + 2 * i]);

        float sn = 0.0f, sp = 0.0f;
#pragma unroll
        for (int e = 0; e < C; ++e) {
            const float ex = __expf(p[e] == 0 ? q[e] : -q[e]);
            sn += (p[e] == 0) ? ex : 0.0f;
            sp += (p[e] == 0) ? 0.0f : ex;
        }
        acc += log1pf(sn * sp);

        __syncthreads();   // protect LDS before next iteration's writes
    }

    // wave64 reduce (6 steps, once per block)
#pragma unroll
    for (int m = 1; m < 64; m <<= 1) acc += __shfl_xor(acc, m, 64);
    if (l == 0) bsum[blockIdx.x] = acc;
}

__global__ __launch_bounds__(256) void lsep_k2(const float* __restrict__ bsum,
                                               float* __restrict__ out) {
    float s = 0.0f;
    for (int i = threadIdx.x; i < NBLK; i += 256) s += bsum[i];
#pragma unroll
    for (int m = 1; m < 64; m <<= 1) s += __shfl_xor(s, m, 64);
    __shared__ float wsum[4];
    const int lane = threadIdx.x & 63, wid = threadIdx.x >> 6;
    if (lane == 0) wsum[wid] = s;
    __syncthreads();
    if (threadIdx.x == 0)
        out[0] = (wsum[0] + wsum[1] + wsum[2] + wsum[3]) * (1.0f / (float)NROWS);
}

extern "C" void kernel_launch(void* const* d_in, const int* in_sizes, int n_in,
                              void* d_out, int out_size, void* d_ws, size_t ws_size,
                              hipStream_t stream) {
    const float* T       = (const float*)d_in[0];
    const int*   bayes   = (const int*)d_in[1];
    const int*   partial = (const int*)d_in[2];
    float*       out     = (float*)d_out;
    float*       bsum    = (float*)d_ws;   // 3125 floats, fully overwritten each call

    lsep_k1<<<NBLK, 64, 0, stream>>>(T, bayes, partial, bsum);
    lsep_k2<<<1, 256, 0, stream>>>(bsum, out);
}